// Round 1
// baseline (576.036 us; speedup 1.0000x reference)
//
#include <hip/hip_runtime.h>
#include <cmath>

#define IH 128
#define IW 128
#define IC 64
#define NB 8
#define NKF 9
#define NOC 64   // deform output channels
#define NOM 27   // offset(18)+mask(9) channels

// ws layout (float elements):
//   offm : [NB][27][IH][IW]           = 8*27*16384   = 3538944
//   wt_dc: [9][64][64]  (k,c,o)       = 36864
//   wt_om: [9][64][32]  (k,c,o pad27) = 18432
#define OFFM_OFF 0
#define WTDC_OFF 3538944
#define WTOM_OFF (3538944 + 36864)

// ---------------------------------------------------------------------------
// Kernel 0: transpose weights to [k][c][o] for coalesced LDS staging
// ---------------------------------------------------------------------------
__global__ void transpose_weights(const float* __restrict__ w_dc,
                                  const float* __restrict__ w_om,
                                  float* __restrict__ ws) {
    int idx = blockIdx.x * blockDim.x + threadIdx.x;
    if (idx < 9 * 64 * 64) {
        int k = idx >> 12;
        int c = (idx >> 6) & 63;
        int o = idx & 63;
        ws[WTDC_OFF + idx] = w_dc[(o * 64 + c) * 9 + k];
    }
    if (idx < 9 * 64 * 32) {
        int k = idx >> 11;
        int c = (idx >> 5) & 63;
        int o = idx & 31;
        ws[WTOM_OFF + idx] = (o < 27) ? w_om[(o * 64 + c) * 9 + k] : 0.0f;
    }
}

// ---------------------------------------------------------------------------
// Kernel 1: conv3x3 -> offset/mask. Tiled GEMM: tile 128px x 32o, thread 4x4.
// One block per (b, row). Writes offsets raw, masks as 2*sigmoid.
// ---------------------------------------------------------------------------
__global__ __launch_bounds__(256) void conv_om_kernel(
        const float* __restrict__ x,
        const float* __restrict__ b_om,
        const float* __restrict__ wt_om,   // [9][64][32]
        float* __restrict__ offm) {
    __shared__ __align__(16) float AT[64 * 128];  // [c][px]
    __shared__ __align__(16) float BT[64 * 32];   // [c][o]

    const int tid = threadIdx.x;
    const int blk = blockIdx.x;
    const int b = blk >> 7;
    const int h = blk & 127;

    const int tx = tid & 31;        // px group: px0 = tx*4
    const int tyo = tid >> 5;       // o group:  o0  = tyo*4 (0..28)
    const int px0 = tx << 2;
    const int o0 = tyo << 2;

    float acc[4][4];
#pragma unroll
    for (int j = 0; j < 4; ++j) {
        float bias = (o0 + j < 27) ? b_om[o0 + j] : 0.0f;
#pragma unroll
        for (int i = 0; i < 4; ++i) acc[i][j] = bias;
    }

    for (int k = 0; k < 9; ++k) {
        __syncthreads();
        // stage B tile (coalesced from transposed weights)
        for (int i = tid; i < 2048; i += 256) BT[i] = wt_om[(k << 11) + i];
        // stage A tile: shifted x row
        const int kh = k / 3;
        const int kw = k - kh * 3;
        const int y = h + kh - 1;
        const bool yv = (y >= 0) && (y < IH);
        for (int i = tid; i < 8192; i += 256) {
            const int c = i >> 7;
            const int px = i & 127;
            float v = 0.0f;
            if (yv) {
                const int xc = px + kw - 1;
                if (xc >= 0 && xc < IW)
                    v = x[(((size_t)(b * 64 + c)) << 14) + (y << 7) + xc];
            }
            AT[i] = v;
        }
        __syncthreads();
#pragma unroll 8
        for (int c = 0; c < 64; ++c) {
            const float4 a = *(const float4*)&AT[(c << 7) + px0];
            const float4 wv = *(const float4*)&BT[(c << 5) + o0];
            acc[0][0] += a.x * wv.x; acc[0][1] += a.x * wv.y; acc[0][2] += a.x * wv.z; acc[0][3] += a.x * wv.w;
            acc[1][0] += a.y * wv.x; acc[1][1] += a.y * wv.y; acc[1][2] += a.y * wv.z; acc[1][3] += a.y * wv.w;
            acc[2][0] += a.z * wv.x; acc[2][1] += a.z * wv.y; acc[2][2] += a.z * wv.z; acc[2][3] += a.z * wv.w;
            acc[3][0] += a.w * wv.x; acc[3][1] += a.w * wv.y; acc[3][2] += a.w * wv.z; acc[3][3] += a.w * wv.w;
        }
    }

    // epilogue: offsets raw, masks 2*sigmoid
    const size_t pbase = ((size_t)(b * 27) << 14) + (h << 7) + px0;
#pragma unroll
    for (int j = 0; j < 4; ++j) {
        const int o = o0 + j;
        if (o >= 27) continue;
        float4 r;
        r.x = acc[0][j]; r.y = acc[1][j]; r.z = acc[2][j]; r.w = acc[3][j];
        if (o >= 18) {
            r.x = 2.0f / (1.0f + expf(-r.x));
            r.y = 2.0f / (1.0f + expf(-r.y));
            r.z = 2.0f / (1.0f + expf(-r.z));
            r.w = 2.0f / (1.0f + expf(-r.w));
        }
        *(float4*)&offm[pbase + ((size_t)o << 14)] = r;
    }
}

// ---------------------------------------------------------------------------
// Kernel 2: deformable conv. Block = 64px x 64o tile, thread 4x4.
// Per k: gather bilinear samples into LDS (vmT[c][px]), weights [c][o], GEMM.
// ---------------------------------------------------------------------------
__global__ __launch_bounds__(256) void deform_kernel(
        const float* __restrict__ x,
        const float* __restrict__ b_dc,
        const float* __restrict__ offm,    // [B][27][H][W]
        const float* __restrict__ wt_dc,   // [9][64][64] (k,c,o)
        float* __restrict__ out) {
    __shared__ __align__(16) float offs[27 * 64];   // [ch][px]
    __shared__ __align__(16) float vmT[64 * 64];    // [c][px]
    __shared__ __align__(16) float wks[64 * 64];    // [c][o]

    const int tid = threadIdx.x;
    const int blk = blockIdx.x;
    const int b = blk >> 8;          // 256 blocks per image
    const int rem = blk & 255;
    const int h = rem >> 1;
    const int w0 = (rem & 1) << 6;

    // stage offsets/masks for the 64 pixels of this tile
    for (int i = tid; i < 1728; i += 256) {
        const int ch = i >> 6;
        const int px = i & 63;
        offs[i] = offm[(((size_t)(b * 27 + ch)) << 14) + (h << 7) + w0 + px];
    }

    const int px = tid & 63;     // gather role: pixel
    const int cg = tid >> 6;     // gather role: channel group (16 ch)
    const int tx = tid & 15;     // gemm role: px0 = tx*4
    const int tyo = tid >> 4;    // gemm role: o0 = tyo*4
    const int px0 = tx << 2;
    const int o0 = tyo << 2;

    float acc[4][4];
#pragma unroll
    for (int j = 0; j < 4; ++j) {
        const float bias = b_dc[o0 + j];
#pragma unroll
        for (int i = 0; i < 4; ++i) acc[i][j] = bias;
    }

    for (int k = 0; k < 9; ++k) {
        __syncthreads();   // previous GEMM done (and offs staged, for k=0)
        // stage weight slice [c][o] for this k
        for (int i = tid; i < 4096; i += 256) wks[i] = wt_dc[(k << 12) + i];

        // gather: this thread produces 16 channels for pixel `px`
        const float offy = offs[((k << 1)) * 64 + px];
        const float offx = offs[((k << 1) + 1) * 64 + px];
        const float m = offs[(18 + k) * 64 + px];
        const int kh = k / 3;
        const int kw = k - kh * 3;
        const float py = (float)(h + kh - 1) + offy;
        const float pxf = (float)(w0 + px + kw - 1) + offx;
        const float y0f = floorf(py);
        const float x0f = floorf(pxf);
        const float fy = py - y0f;
        const float fx = pxf - x0f;
        const float wy0 = 1.0f - fy, wx0 = 1.0f - fx;
        const float vy0 = (y0f >= 0.0f && y0f <= 127.0f) ? 1.0f : 0.0f;
        const float vy1 = (y0f >= -1.0f && y0f <= 126.0f) ? 1.0f : 0.0f;
        const float vx0 = (x0f >= 0.0f && x0f <= 127.0f) ? 1.0f : 0.0f;
        const float vx1 = (x0f >= -1.0f && x0f <= 126.0f) ? 1.0f : 0.0f;
        float w00 = wy0 * wx0 * vy0 * vx0;
        float w01 = wy0 * fx  * vy0 * vx1;
        float w10 = fy  * wx0 * vy1 * vx0;
        float w11 = fy  * fx  * vy1 * vx1;
        const int y0i = min(max((int)y0f, 0), 127);
        const int y1i = min(max((int)y0f + 1, 0), 127);
        const int x0i = min(max((int)x0f, 0), 127);
        const int x1i = min(max((int)x0f + 1, 0), 127);
        const int o00 = (y0i << 7) + x0i;
        const int o01 = (y0i << 7) + x1i;
        const int o10 = (y1i << 7) + x0i;
        const int o11 = (y1i << 7) + x1i;
        const float* xb = x + (((size_t)(b * 64 + cg * 16)) << 14);
#pragma unroll
        for (int i = 0; i < 16; ++i) {
            const float v = w00 * xb[o00] + w01 * xb[o01] +
                            w10 * xb[o10] + w11 * xb[o11];
            vmT[((cg * 16 + i) << 6) + px] = v * m;
            xb += 16384;
        }
        __syncthreads();
#pragma unroll 8
        for (int c = 0; c < 64; ++c) {
            const float4 a = *(const float4*)&vmT[(c << 6) + px0];
            const float4 wv = *(const float4*)&wks[(c << 6) + o0];
            acc[0][0] += a.x * wv.x; acc[0][1] += a.x * wv.y; acc[0][2] += a.x * wv.z; acc[0][3] += a.x * wv.w;
            acc[1][0] += a.y * wv.x; acc[1][1] += a.y * wv.y; acc[1][2] += a.y * wv.z; acc[1][3] += a.y * wv.w;
            acc[2][0] += a.z * wv.x; acc[2][1] += a.z * wv.y; acc[2][2] += a.z * wv.z; acc[2][3] += a.z * wv.w;
            acc[3][0] += a.w * wv.x; acc[3][1] += a.w * wv.y; acc[3][2] += a.w * wv.z; acc[3][3] += a.w * wv.w;
        }
    }

    // epilogue: out[b][o][h][w0+px]
    const size_t obase = (((size_t)(b * 64)) << 14) + (h << 7) + w0 + px0;
#pragma unroll
    for (int j = 0; j < 4; ++j) {
        const int o = o0 + j;
        float4 r;
        r.x = acc[0][j]; r.y = acc[1][j]; r.z = acc[2][j]; r.w = acc[3][j];
        *(float4*)&out[obase + ((size_t)o << 14)] = r;
    }
}

extern "C" void kernel_launch(void* const* d_in, const int* in_sizes, int n_in,
                              void* d_out, int out_size, void* d_ws, size_t ws_size,
                              hipStream_t stream) {
    const float* x    = (const float*)d_in[0];
    const float* w_om = (const float*)d_in[1];
    const float* b_om = (const float*)d_in[2];
    const float* w_dc = (const float*)d_in[3];
    const float* b_dc = (const float*)d_in[4];
    float* out = (float*)d_out;
    float* ws  = (float*)d_ws;

    float* offm  = ws + OFFM_OFF;
    float* wt_dc = ws + WTDC_OFF;
    float* wt_om = ws + WTOM_OFF;

    transpose_weights<<<216, 256, 0, stream>>>(w_dc, w_om, ws);
    conv_om_kernel<<<NB * IH, 256, 0, stream>>>(x, b_om, wt_om, offm);
    deform_kernel<<<NB * IH * 2, 256, 0, stream>>>(x, b_dc, offm, wt_dc, out);
}

// Round 3
// 368.789 us; speedup vs baseline: 1.5620x; 1.5620x over previous
//
#include <hip/hip_runtime.h>
#include <cmath>

#define IH 128
#define IW 128
#define IC 64
#define NB 8
#define NKF 9
#define NOC 64   // deform output channels
#define NOM 27   // offset(18)+mask(9) channels

// ws layout (float elements):
//   offm : [NB][27][IH][IW]           = 3538944
//   wt_dc: [9][64][64]  (k,c,o)       = 36864
//   wt_om: [9][64][32]  (k,c,o pad27) = 18432
//   xT   : [NB][IH][IW][64] bf16      = 8388608 u16 = 4194304 float slots
#define OFFM_OFF 0
#define WTDC_OFF 3538944
#define WTOM_OFF (3538944 + 36864)
#define XT_OFF   (3538944 + 36864 + 18432)

// fp32 -> bf16 bits, round-to-nearest-even
__device__ __forceinline__ unsigned short f32_to_bf16(float f) {
    unsigned int u = __float_as_uint(f);
    u += 0x7fffu + ((u >> 16) & 1u);
    return (unsigned short)(u >> 16);
}

// ---------------------------------------------------------------------------
// Kernel 0: transpose weights to [k][c][o] for coalesced LDS staging
// ---------------------------------------------------------------------------
__global__ void transpose_weights(const float* __restrict__ w_dc,
                                  const float* __restrict__ w_om,
                                  float* __restrict__ ws) {
    int idx = blockIdx.x * blockDim.x + threadIdx.x;
    if (idx < 9 * 64 * 64) {
        int k = idx >> 12;
        int c = (idx >> 6) & 63;
        int o = idx & 63;
        ws[WTDC_OFF + idx] = w_dc[(o * 64 + c) * 9 + k];
    }
    if (idx < 9 * 64 * 32) {
        int k = idx >> 11;
        int c = (idx >> 5) & 63;
        int o = idx & 31;
        ws[WTOM_OFF + idx] = (o < 27) ? w_om[(o * 64 + c) * 9 + k] : 0.0f;
    }
}

// ---------------------------------------------------------------------------
// Kernel 0b: transpose x NCHW fp32 -> NHWC bf16 (xT[b][y][x][c])
// Block = (b, h, 64-wide w segment). LDS tile 64x64 transposed, pad 65.
// ---------------------------------------------------------------------------
__global__ __launch_bounds__(256) void transpose_x(
        const float* __restrict__ x, unsigned short* __restrict__ xT) {
    __shared__ float t[64 * 65];
    const int tid = threadIdx.x;
    const int blk = blockIdx.x;
    const int b = blk >> 8;
    const int rem = blk & 255;
    const int h = rem >> 1;
    const int w0 = (rem & 1) << 6;

    for (int i = tid; i < 4096; i += 256) {
        const int c = i >> 6;
        const int w = i & 63;
        t[w * 65 + c] = x[(((size_t)(b * 64 + c)) << 14) + (h << 7) + w0 + w];
    }
    __syncthreads();
    const int c2 = (tid & 31) * 2;
    ushort2* dst = (ushort2*)(xT + (((size_t)b << 20)) + ((size_t)((h << 7) + w0)) * 64 + c2);
#pragma unroll
    for (int p = 0; p < 8; ++p) {
        const int w = (tid >> 5) + p * 8;
        ushort2 u;
        u.x = f32_to_bf16(t[w * 65 + c2]);
        u.y = f32_to_bf16(t[w * 65 + c2 + 1]);
        dst[(size_t)w * 32] = u;
    }
}

// ---------------------------------------------------------------------------
// Kernel 1: conv3x3 -> offset/mask. Tiled GEMM: tile 128px x 32o, thread 4x4.
// ---------------------------------------------------------------------------
__global__ __launch_bounds__(256) void conv_om_kernel(
        const float* __restrict__ x,
        const float* __restrict__ b_om,
        const float* __restrict__ wt_om,   // [9][64][32]
        float* __restrict__ offm) {
    __shared__ __align__(16) float AT[64 * 128];  // [c][px]
    __shared__ __align__(16) float BT[64 * 32];   // [c][o]

    const int tid = threadIdx.x;
    const int blk = blockIdx.x;
    const int b = blk >> 7;
    const int h = blk & 127;

    const int tx = tid & 31;
    const int tyo = tid >> 5;
    const int px0 = tx << 2;
    const int o0 = tyo << 2;

    float acc[4][4];
#pragma unroll
    for (int j = 0; j < 4; ++j) {
        float bias = (o0 + j < 27) ? b_om[o0 + j] : 0.0f;
#pragma unroll
        for (int i = 0; i < 4; ++i) acc[i][j] = bias;
    }

    for (int k = 0; k < 9; ++k) {
        __syncthreads();
        for (int i = tid; i < 2048; i += 256) BT[i] = wt_om[(k << 11) + i];
        const int kh = k / 3;
        const int kw = k - kh * 3;
        const int y = h + kh - 1;
        const bool yv = (y >= 0) && (y < IH);
        for (int i = tid; i < 8192; i += 256) {
            const int c = i >> 7;
            const int px = i & 127;
            float v = 0.0f;
            if (yv) {
                const int xc = px + kw - 1;
                if (xc >= 0 && xc < IW)
                    v = x[(((size_t)(b * 64 + c)) << 14) + (y << 7) + xc];
            }
            AT[i] = v;
        }
        __syncthreads();
#pragma unroll 8
        for (int c = 0; c < 64; ++c) {
            const float4 a = *(const float4*)&AT[(c << 7) + px0];
            const float4 wv = *(const float4*)&BT[(c << 5) + o0];
            acc[0][0] += a.x * wv.x; acc[0][1] += a.x * wv.y; acc[0][2] += a.x * wv.z; acc[0][3] += a.x * wv.w;
            acc[1][0] += a.y * wv.x; acc[1][1] += a.y * wv.y; acc[1][2] += a.y * wv.z; acc[1][3] += a.y * wv.w;
            acc[2][0] += a.z * wv.x; acc[2][1] += a.z * wv.y; acc[2][2] += a.z * wv.z; acc[2][3] += a.z * wv.w;
            acc[3][0] += a.w * wv.x; acc[3][1] += a.w * wv.y; acc[3][2] += a.w * wv.z; acc[3][3] += a.w * wv.w;
        }
    }

    const size_t pbase = ((size_t)(b * 27) << 14) + (h << 7) + px0;
#pragma unroll
    for (int j = 0; j < 4; ++j) {
        const int o = o0 + j;
        if (o >= 27) continue;
        float4 r;
        r.x = acc[0][j]; r.y = acc[1][j]; r.z = acc[2][j]; r.w = acc[3][j];
        if (o >= 18) {
            r.x = 2.0f / (1.0f + expf(-r.x));
            r.y = 2.0f / (1.0f + expf(-r.y));
            r.z = 2.0f / (1.0f + expf(-r.z));
            r.w = 2.0f / (1.0f + expf(-r.w));
        }
        *(float4*)&offm[pbase + ((size_t)o << 14)] = r;
    }
}

// ---------------------------------------------------------------------------
// bilinear corner accumulate: 16 channels (bf16 bits, NHWC) at position pos
// ---------------------------------------------------------------------------
__device__ __forceinline__ void corner_acc(const unsigned short* __restrict__ xb,
                                           int pos, int cg, float wgt, float* v) {
    const uint4* p = (const uint4*)(xb + ((size_t)pos << 6) + (cg << 4));
    const uint4 a = p[0];
    const uint4 b = p[1];
    unsigned int u[8] = {a.x, a.y, a.z, a.w, b.x, b.y, b.z, b.w};
#pragma unroll
    for (int i = 0; i < 8; ++i) {
        v[2 * i]     += wgt * __uint_as_float(u[i] << 16);
        v[2 * i + 1] += wgt * __uint_as_float(u[i] & 0xffff0000u);
    }
}

// ---------------------------------------------------------------------------
// Kernel 2: deformable conv. Block = 64px x 64o tile, thread 4x4.
// Gather reads NHWC bf16 xT (contiguous 128B per sample position).
// ---------------------------------------------------------------------------
__global__ __launch_bounds__(256) void deform_kernel(
        const unsigned short* __restrict__ xT,
        const float* __restrict__ b_dc,
        const float* __restrict__ offm,    // [B][27][H][W]
        const float* __restrict__ wt_dc,   // [9][64][64] (k,c,o)
        float* __restrict__ out) {
    __shared__ __align__(16) float offs[27 * 64];   // [ch][px]
    __shared__ __align__(16) float vmT[64 * 64];    // [c][px]
    __shared__ __align__(16) float wks[64 * 64];    // [c][o]

    const int tid = threadIdx.x;
    const int blk = blockIdx.x;
    const int b = blk >> 8;
    const int rem = blk & 255;
    const int h = rem >> 1;
    const int w0 = (rem & 1) << 6;

    for (int i = tid; i < 1728; i += 256) {
        const int ch = i >> 6;
        const int px = i & 63;
        offs[i] = offm[(((size_t)(b * 27 + ch)) << 14) + (h << 7) + w0 + px];
    }

    const int px = tid & 63;     // gather role: pixel
    const int cg = tid >> 6;     // gather role: channel group (16 ch)
    const int tx = tid & 15;     // gemm role
    const int tyo = tid >> 4;
    const int px0 = tx << 2;
    const int o0 = tyo << 2;

    const unsigned short* xb = xT + ((size_t)b << 20);

    float acc[4][4];
#pragma unroll
    for (int j = 0; j < 4; ++j) {
        const float bias = b_dc[o0 + j];
#pragma unroll
        for (int i = 0; i < 4; ++i) acc[i][j] = bias;
    }

    for (int k = 0; k < 9; ++k) {
        __syncthreads();
        for (int i = tid; i < 4096; i += 256) wks[i] = wt_dc[(k << 12) + i];

        const float offy = offs[((k << 1)) * 64 + px];
        const float offx = offs[((k << 1) + 1) * 64 + px];
        const float m = offs[(18 + k) * 64 + px];
        const int kh = k / 3;
        const int kw = k - kh * 3;
        const float py = (float)(h + kh - 1) + offy;
        const float pxf = (float)(w0 + px + kw - 1) + offx;
        const float y0f = floorf(py);
        const float x0f = floorf(pxf);
        const float fy = py - y0f;
        const float fx = pxf - x0f;
        const float wy0 = 1.0f - fy, wx0 = 1.0f - fx;
        const float vy0 = (y0f >= 0.0f && y0f <= 127.0f) ? 1.0f : 0.0f;
        const float vy1 = (y0f >= -1.0f && y0f <= 126.0f) ? 1.0f : 0.0f;
        const float vx0 = (x0f >= 0.0f && x0f <= 127.0f) ? 1.0f : 0.0f;
        const float vx1 = (x0f >= -1.0f && x0f <= 126.0f) ? 1.0f : 0.0f;
        const float w00 = wy0 * wx0 * vy0 * vx0;
        const float w01 = wy0 * fx  * vy0 * vx1;
        const float w10 = fy  * wx0 * vy1 * vx0;
        const float w11 = fy  * fx  * vy1 * vx1;
        const int y0i = min(max((int)y0f, 0), 127);
        const int y1i = min(max((int)y0f + 1, 0), 127);
        const int x0i = min(max((int)x0f, 0), 127);
        const int x1i = min(max((int)x0f + 1, 0), 127);

        float v[16];
#pragma unroll
        for (int i = 0; i < 16; ++i) v[i] = 0.0f;
        corner_acc(xb, (y0i << 7) + x0i, cg, w00, v);
        corner_acc(xb, (y0i << 7) + x1i, cg, w01, v);
        corner_acc(xb, (y1i << 7) + x0i, cg, w10, v);
        corner_acc(xb, (y1i << 7) + x1i, cg, w11, v);
#pragma unroll
        for (int i = 0; i < 16; ++i)
            vmT[((cg * 16 + i) << 6) + px] = v[i] * m;

        __syncthreads();
#pragma unroll 8
        for (int c = 0; c < 64; ++c) {
            const float4 a = *(const float4*)&vmT[(c << 6) + px0];
            const float4 wv = *(const float4*)&wks[(c << 6) + o0];
            acc[0][0] += a.x * wv.x; acc[0][1] += a.x * wv.y; acc[0][2] += a.x * wv.z; acc[0][3] += a.x * wv.w;
            acc[1][0] += a.y * wv.x; acc[1][1] += a.y * wv.y; acc[1][2] += a.y * wv.z; acc[1][3] += a.y * wv.w;
            acc[2][0] += a.z * wv.x; acc[2][1] += a.z * wv.y; acc[2][2] += a.z * wv.z; acc[2][3] += a.z * wv.w;
            acc[3][0] += a.w * wv.x; acc[3][1] += a.w * wv.y; acc[3][2] += a.w * wv.z; acc[3][3] += a.w * wv.w;
        }
    }

    const size_t obase = (((size_t)(b * 64)) << 14) + (h << 7) + w0 + px0;
#pragma unroll
    for (int j = 0; j < 4; ++j) {
        const int o = o0 + j;
        float4 r;
        r.x = acc[0][j]; r.y = acc[1][j]; r.z = acc[2][j]; r.w = acc[3][j];
        *(float4*)&out[obase + ((size_t)o << 14)] = r;
    }
}

extern "C" void kernel_launch(void* const* d_in, const int* in_sizes, int n_in,
                              void* d_out, int out_size, void* d_ws, size_t ws_size,
                              hipStream_t stream) {
    const float* x    = (const float*)d_in[0];
    const float* w_om = (const float*)d_in[1];
    const float* b_om = (const float*)d_in[2];
    const float* w_dc = (const float*)d_in[3];
    const float* b_dc = (const float*)d_in[4];
    float* out = (float*)d_out;
    float* ws  = (float*)d_ws;

    float* offm  = ws + OFFM_OFF;
    float* wt_dc = ws + WTDC_OFF;
    float* wt_om = ws + WTOM_OFF;
    unsigned short* xT = (unsigned short*)(ws + XT_OFF);

    transpose_weights<<<216, 256, 0, stream>>>(w_dc, w_om, ws);
    transpose_x<<<NB * IH * 2, 256, 0, stream>>>(x, xT);
    conv_om_kernel<<<NB * IH, 256, 0, stream>>>(x, b_om, wt_om, offm);
    deform_kernel<<<NB * IH * 2, 256, 0, stream>>>(xT, b_dc, offm, wt_dc, out);
}

// Round 4
// 194.790 us; speedup vs baseline: 2.9572x; 1.8933x over previous
//
#include <hip/hip_runtime.h>
#include <cmath>

#define IH 128
#define IW 128
#define NB 8

typedef __attribute__((ext_vector_type(8))) short bf16x8;
typedef __attribute__((ext_vector_type(4))) float f32x4;

// ws layout (float slots):
//   offm  : [NB][27][IH][IW] f32      = 3538944
//   xT    : [NB][IH][IW][64] bf16     = 4194304 float slots (8388608 u16)
//   wt_dc : [9][64][64] bf16 (k,o,c)  = 18432 float slots
//   wt_om : [9][32][64] bf16 (k,o,c)  = 9216  float slots
#define OFFM_OFF 0
#define XT_OFF   3538944
#define WTDC_OFF (3538944 + 4194304)
#define WTOM_OFF (3538944 + 4194304 + 18432)

// fp32 -> bf16 bits, round-to-nearest-even
__device__ __forceinline__ unsigned short f32_to_bf16(float f) {
    unsigned int u = __float_as_uint(f);
    u += 0x7fffu + ((u >> 16) & 1u);
    return (unsigned short)(u >> 16);
}

// ---------------------------------------------------------------------------
// Kernel 0: weights -> bf16, layout [k][o][c] (B^T for MFMA b-frags)
// ---------------------------------------------------------------------------
__global__ void transpose_weights(const float* __restrict__ w_dc,
                                  const float* __restrict__ w_om,
                                  unsigned short* __restrict__ wt_dc16,
                                  unsigned short* __restrict__ wt_om16) {
    int idx = blockIdx.x * blockDim.x + threadIdx.x;
    if (idx < 9 * 64 * 64) {
        int k = idx >> 12;
        int o = (idx >> 6) & 63;
        int c = idx & 63;
        wt_dc16[idx] = f32_to_bf16(w_dc[(o * 64 + c) * 9 + k]);
    }
    if (idx < 9 * 32 * 64) {
        int k = idx >> 11;
        int o = (idx >> 6) & 31;
        int c = idx & 63;
        wt_om16[idx] = (o < 27) ? f32_to_bf16(w_om[(o * 64 + c) * 9 + k])
                                : (unsigned short)0;
    }
}

// ---------------------------------------------------------------------------
// Kernel 0b: x NCHW fp32 -> NHWC bf16 (xT[b][y][x][c])
// ---------------------------------------------------------------------------
__global__ __launch_bounds__(256) void transpose_x(
        const float* __restrict__ x, unsigned short* __restrict__ xT) {
    __shared__ float t[64 * 65];
    const int tid = threadIdx.x;
    const int blk = blockIdx.x;
    const int b = blk >> 8;
    const int rem = blk & 255;
    const int h = rem >> 1;
    const int w0 = (rem & 1) << 6;

    for (int i = tid; i < 4096; i += 256) {
        const int c = i >> 6;
        const int w = i & 63;
        t[w * 65 + c] = x[(((size_t)(b * 64 + c)) << 14) + (h << 7) + w0 + w];
    }
    __syncthreads();
    const int c2 = (tid & 31) * 2;
    ushort2* dst = (ushort2*)(xT + (((size_t)b << 20)) + ((size_t)((h << 7) + w0)) * 64 + c2);
#pragma unroll
    for (int p = 0; p < 8; ++p) {
        const int w = (tid >> 5) + p * 8;
        ushort2 u;
        u.x = f32_to_bf16(t[w * 65 + c2]);
        u.y = f32_to_bf16(t[w * 65 + c2 + 1]);
        dst[(size_t)w * 32] = u;
    }
}

// ---------------------------------------------------------------------------
// Kernel 1: conv3x3 -> offset/mask via MFMA. Block = 64px x 32o (27 used).
// Window [3][66][64ch] staged once; per-k weight slice [32][64ch].
// ---------------------------------------------------------------------------
__global__ __launch_bounds__(256) void conv_om_mfma(
        const unsigned short* __restrict__ xT,
        const float* __restrict__ b_om,
        const unsigned short* __restrict__ wt_om16,  // [9][32][64]
        float* __restrict__ offm) {
    __shared__ __align__(16) unsigned short win[198 * 72];  // [3*66][72]
    __shared__ __align__(16) unsigned short wks[32 * 72];   // [o][72]

    const int tid = threadIdx.x;
    const int b = blockIdx.x >> 8;
    const int rem = blockIdx.x & 255;
    const int h = rem >> 1;
    const int w0 = (rem & 1) << 6;

    // stage 3-row, 66-px window of xT (zero-padded at borders)
    for (int idx = tid; idx < 1584; idx += 256) {
        const int pos = idx >> 3;
        const int part = idx & 7;
        const int r = pos / 66;
        const int xx = pos - r * 66;
        const int y = h + r - 1;
        const int xg = w0 + xx - 1;
        uint4 v = make_uint4(0u, 0u, 0u, 0u);
        if (y >= 0 && y < IH && xg >= 0 && xg < IW)
            v = *(const uint4*)(xT + (((size_t)b << 20) + (((y << 7) + xg) << 6) + (part << 3)));
        *(uint4*)&win[pos * 72 + part * 8] = v;
    }

    const int wid = tid >> 6;      // px tile 0..3
    const int lane = tid & 63;
    const int ln15 = lane & 15;
    const int quad = lane >> 4;

    f32x4 acc[2] = {{0.f, 0.f, 0.f, 0.f}, {0.f, 0.f, 0.f, 0.f}};

    for (int k = 0; k < 9; ++k) {
        __syncthreads();
        {   // stage weight slice: 32 o x 64 c bf16
            const int o = tid >> 3;
            const int part = tid & 7;
            *(uint4*)&wks[o * 72 + part * 8] =
                *(const uint4*)(wt_om16 + (k << 11) + (o << 6) + (part << 3));
        }
        __syncthreads();
        const int kh = k / 3;
        const int kw = k - kh * 3;
        const int posb = kh * 66 + wid * 16 + ln15 + kw;
#pragma unroll
        for (int ch = 0; ch < 2; ++ch) {
            const int c = (ch << 5) + (quad << 3);
            const bf16x8 a  = *(const bf16x8*)&win[posb * 72 + c];
            const bf16x8 b0 = *(const bf16x8*)&wks[ln15 * 72 + c];
            const bf16x8 b1 = *(const bf16x8*)&wks[(16 + ln15) * 72 + c];
            acc[0] = __builtin_amdgcn_mfma_f32_16x16x32_bf16(a, b0, acc[0], 0, 0, 0);
            acc[1] = __builtin_amdgcn_mfma_f32_16x16x32_bf16(a, b1, acc[1], 0, 0, 0);
        }
    }

    // epilogue: C/D layout col(o)=lane&15, row(px)=quad*4+reg
    const int px0 = wid * 16 + quad * 4;
#pragma unroll
    for (int ot = 0; ot < 2; ++ot) {
        const int o = ot * 16 + ln15;
        if (o >= 27) continue;
        const float bias = b_om[o];
        float4 r;
        r.x = acc[ot][0] + bias;
        r.y = acc[ot][1] + bias;
        r.z = acc[ot][2] + bias;
        r.w = acc[ot][3] + bias;
        if (o >= 18) {
            r.x = 2.0f / (1.0f + __expf(-r.x));
            r.y = 2.0f / (1.0f + __expf(-r.y));
            r.z = 2.0f / (1.0f + __expf(-r.z));
            r.w = 2.0f / (1.0f + __expf(-r.w));
        }
        *(float4*)&offm[(((size_t)(b * 27 + o)) << 14) + (h << 7) + w0 + px0] = r;
    }
}

// ---------------------------------------------------------------------------
// bilinear corner accumulate: 16 channels (bf16 bits, NHWC) at position pos
// ---------------------------------------------------------------------------
__device__ __forceinline__ void corner_acc(const unsigned short* __restrict__ xb,
                                           int pos, int cg, float wgt, float* v) {
    const uint4* p = (const uint4*)(xb + ((size_t)pos << 6) + (cg << 4));
    const uint4 a = p[0];
    const uint4 b = p[1];
    unsigned int u[8] = {a.x, a.y, a.z, a.w, b.x, b.y, b.z, b.w};
#pragma unroll
    for (int i = 0; i < 8; ++i) {
        v[2 * i]     += wgt * __uint_as_float(u[i] << 16);
        v[2 * i + 1] += wgt * __uint_as_float(u[i] & 0xffff0000u);
    }
}

// ---------------------------------------------------------------------------
// Kernel 2: deformable conv via MFMA. Block = 64px x 64o.
// Gather -> vm[px][c] bf16 (mask folded), weights wks[o][c] bf16,
// 4 waves x (2x2) 16x16x32 MFMA tiles.
// ---------------------------------------------------------------------------
__global__ __launch_bounds__(256) void deform_mfma(
        const unsigned short* __restrict__ xT,
        const float* __restrict__ b_dc,
        const float* __restrict__ offm,              // [B][27][H][W]
        const unsigned short* __restrict__ wt_dc16,  // [9][64][64] (k,o,c)
        float* __restrict__ out) {
    __shared__ __align__(16) float offs[27 * 64];          // [ch][px]
    __shared__ __align__(16) unsigned short vm[64 * 72];   // [px][c pad]
    __shared__ __align__(16) unsigned short wks[64 * 72];  // [o][c pad]

    const int tid = threadIdx.x;
    const int b = blockIdx.x >> 8;
    const int rem = blockIdx.x & 255;
    const int h = rem >> 1;
    const int w0 = (rem & 1) << 6;

    for (int i = tid; i < 1728; i += 256) {
        const int ch = i >> 6;
        const int px = i & 63;
        offs[i] = offm[(((size_t)(b * 27 + ch)) << 14) + (h << 7) + w0 + px];
    }

    const int px = tid & 63;     // gather role
    const int cg = tid >> 6;     // gather role: 16-channel group
    const int wid = tid >> 6;
    const int lane = tid & 63;
    const int ln15 = lane & 15;
    const int quad = lane >> 4;
    const int pt0 = (wid >> 1) << 1;   // px tile base (2 tiles)
    const int ot0 = (wid & 1) << 1;    // o  tile base (2 tiles)

    const unsigned short* xb = xT + ((size_t)b << 20);

    f32x4 acc[2][2];
#pragma unroll
    for (int i = 0; i < 2; ++i)
#pragma unroll
        for (int j = 0; j < 2; ++j) acc[i][j] = (f32x4){0.f, 0.f, 0.f, 0.f};

    for (int k = 0; k < 9; ++k) {
        __syncthreads();
        // stage weight slice 64o x 64c
        for (int idx = tid; idx < 512; idx += 256) {
            const int o = idx >> 3;
            const int part = idx & 7;
            *(uint4*)&wks[o * 72 + part * 8] =
                *(const uint4*)(wt_dc16 + (k << 12) + (o << 6) + (part << 3));
        }
        // gather 16 channels for pixel px
        const float offy = offs[(k << 1) * 64 + px];
        const float offx = offs[((k << 1) + 1) * 64 + px];
        const float msk = offs[(18 + k) * 64 + px];
        const int kh = k / 3;
        const int kw = k - kh * 3;
        const float py = (float)(h + kh - 1) + offy;
        const float pxf = (float)(w0 + px + kw - 1) + offx;
        const float y0f = floorf(py);
        const float x0f = floorf(pxf);
        const float fy = py - y0f;
        const float fx = pxf - x0f;
        const float wy0 = 1.0f - fy, wx0 = 1.0f - fx;
        const float vy0 = (y0f >= 0.0f && y0f <= 127.0f) ? 1.0f : 0.0f;
        const float vy1 = (y0f >= -1.0f && y0f <= 126.0f) ? 1.0f : 0.0f;
        const float vx0 = (x0f >= 0.0f && x0f <= 127.0f) ? 1.0f : 0.0f;
        const float vx1 = (x0f >= -1.0f && x0f <= 126.0f) ? 1.0f : 0.0f;
        const float w00 = wy0 * wx0 * vy0 * vx0;
        const float w01 = wy0 * fx  * vy0 * vx1;
        const float w10 = fy  * wx0 * vy1 * vx0;
        const float w11 = fy  * fx  * vy1 * vx1;
        const int y0i = min(max((int)y0f, 0), 127);
        const int y1i = min(max((int)y0f + 1, 0), 127);
        const int x0i = min(max((int)x0f, 0), 127);
        const int x1i = min(max((int)x0f + 1, 0), 127);

        float v[16];
#pragma unroll
        for (int i = 0; i < 16; ++i) v[i] = 0.0f;
        corner_acc(xb, (y0i << 7) + x0i, cg, w00, v);
        corner_acc(xb, (y0i << 7) + x1i, cg, w01, v);
        corner_acc(xb, (y1i << 7) + x0i, cg, w10, v);
        corner_acc(xb, (y1i << 7) + x1i, cg, w11, v);

        unsigned int pk[8];
#pragma unroll
        for (int i = 0; i < 8; ++i) {
            const unsigned int lo = f32_to_bf16(v[2 * i] * msk);
            const unsigned int hi = f32_to_bf16(v[2 * i + 1] * msk);
            pk[i] = lo | (hi << 16);
        }
        uint4* vdst = (uint4*)&vm[px * 72 + cg * 16];
        vdst[0] = make_uint4(pk[0], pk[1], pk[2], pk[3]);
        vdst[1] = make_uint4(pk[4], pk[5], pk[6], pk[7]);

        __syncthreads();
#pragma unroll
        for (int ch = 0; ch < 2; ++ch) {
            const int c = (ch << 5) + (quad << 3);
            const bf16x8 a0 = *(const bf16x8*)&vm[(pt0 * 16 + ln15) * 72 + c];
            const bf16x8 a1 = *(const bf16x8*)&vm[((pt0 + 1) * 16 + ln15) * 72 + c];
            const bf16x8 b0 = *(const bf16x8*)&wks[(ot0 * 16 + ln15) * 72 + c];
            const bf16x8 b1 = *(const bf16x8*)&wks[((ot0 + 1) * 16 + ln15) * 72 + c];
            acc[0][0] = __builtin_amdgcn_mfma_f32_16x16x32_bf16(a0, b0, acc[0][0], 0, 0, 0);
            acc[0][1] = __builtin_amdgcn_mfma_f32_16x16x32_bf16(a0, b1, acc[0][1], 0, 0, 0);
            acc[1][0] = __builtin_amdgcn_mfma_f32_16x16x32_bf16(a1, b0, acc[1][0], 0, 0, 0);
            acc[1][1] = __builtin_amdgcn_mfma_f32_16x16x32_bf16(a1, b1, acc[1][1], 0, 0, 0);
        }
    }

    // epilogue
#pragma unroll
    for (int pt = 0; pt < 2; ++pt) {
#pragma unroll
        for (int ot = 0; ot < 2; ++ot) {
            const int o = (ot0 + ot) * 16 + ln15;
            const float bias = b_dc[o];
            const int px0 = (pt0 + pt) * 16 + quad * 4;
            float4 r;
            r.x = acc[pt][ot][0] + bias;
            r.y = acc[pt][ot][1] + bias;
            r.z = acc[pt][ot][2] + bias;
            r.w = acc[pt][ot][3] + bias;
            *(float4*)&out[(((size_t)(b * 64 + o)) << 14) + (h << 7) + w0 + px0] = r;
        }
    }
}

extern "C" void kernel_launch(void* const* d_in, const int* in_sizes, int n_in,
                              void* d_out, int out_size, void* d_ws, size_t ws_size,
                              hipStream_t stream) {
    const float* x    = (const float*)d_in[0];
    const float* w_om = (const float*)d_in[1];
    const float* b_om = (const float*)d_in[2];
    const float* w_dc = (const float*)d_in[3];
    const float* b_dc = (const float*)d_in[4];
    float* out = (float*)d_out;
    float* ws  = (float*)d_ws;

    float* offm = ws + OFFM_OFF;
    unsigned short* xT      = (unsigned short*)(ws + XT_OFF);
    unsigned short* wt_dc16 = (unsigned short*)(ws + WTDC_OFF);
    unsigned short* wt_om16 = (unsigned short*)(ws + WTOM_OFF);

    transpose_weights<<<144, 256, 0, stream>>>(w_dc, w_om, wt_dc16, wt_om16);
    transpose_x<<<NB * IH * 2, 256, 0, stream>>>(x, xT);
    conv_om_mfma<<<NB * IH * 2, 256, 0, stream>>>(xT, b_om, wt_om16, offm);
    deform_mfma<<<NB * IH * 2, 256, 0, stream>>>(xT, b_dc, offm, wt_dc16, out);
}